// Round 2
// baseline (2426.337 us; speedup 1.0000x reference)
//
#include <hip/hip_runtime.h>
#include <hip/hip_bf16.h>
#include <cstdint>
#include <cstddef>

typedef __attribute__((ext_vector_type(8))) short short8;
typedef __attribute__((ext_vector_type(4))) float f32x4;

// Shapes: B=128, T-1=31, E=300, H=512, 3H=1536, V=32000, M_ALL=3968

// ---------------------------------------------------------------------------
// K1: hidden0 = relu(concat(g,t) @ W_feat + b_feat)   [128,256]@[256,512]
__global__ __launch_bounds__(512) void k_hidden0(
    const float* __restrict__ g_feat, const float* __restrict__ t_feat,
    const float* __restrict__ W_feat, const float* __restrict__ b_feat,
    float* __restrict__ h_cur) {
  __shared__ float inp[256];
  const int b = blockIdx.x;
  const int tid = threadIdx.x;  // 512
  if (tid < 128) inp[tid] = g_feat[b * 128 + tid];
  else if (tid < 256) inp[tid] = t_feat[b * 128 + tid - 128];
  __syncthreads();
  float acc = b_feat[tid];
#pragma unroll 8
  for (int k = 0; k < 256; ++k) acc = fmaf(inp[k], W_feat[k * 512 + tid], acc);
  h_cur[b * 512 + tid] = fmaxf(acc, 0.f);
}

// ---------------------------------------------------------------------------
// K2: gi_all[r=t*128+b][g] = x(t,b) @ W_ih^T + b_ih (+ b_hh for r,z gates)
// M=3968, N=1536, K=300. fp32 tiled SGEMM, BM=BN=64, BK=16, 4x4 micro.
__global__ __launch_bounds__(256) void k_gi(
    const float* __restrict__ lang, const float* __restrict__ W_ih,
    const float* __restrict__ b_ih, const float* __restrict__ b_hh,
    float* __restrict__ gi_all) {
  __shared__ float As[16][65];  // [k][m]
  __shared__ float Bs[16][65];  // [k][n]
  const int n0 = blockIdx.x * 64;
  const int m0 = blockIdx.y * 64;
  const int tid = threadIdx.x;
  const int tx = tid & 15, ty = tid >> 4;
  float acc[4][4] = {};
  for (int k0 = 0; k0 < 300; k0 += 16) {
    const int kk = tid & 15;
    const int r0 = tid >> 4;
    const int kg = k0 + kk;
    const bool kv = kg < 300;
#pragma unroll
    for (int i = 0; i < 4; ++i) {
      int row = r0 + i * 16;
      int r = m0 + row;
      int t = r >> 7, b = r & 127;
      As[kk][row] = kv ? lang[(size_t)b * 9600 + t * 300 + kg] : 0.f;
    }
#pragma unroll
    for (int i = 0; i < 4; ++i) {
      int n = r0 + i * 16;
      Bs[kk][n] = kv ? W_ih[(size_t)(n0 + n) * 300 + kg] : 0.f;
    }
    __syncthreads();
#pragma unroll
    for (int k = 0; k < 16; ++k) {
      float a[4], b[4];
#pragma unroll
      for (int i = 0; i < 4; ++i) a[i] = As[k][ty * 4 + i];
#pragma unroll
      for (int j = 0; j < 4; ++j) b[j] = Bs[k][tx * 4 + j];
#pragma unroll
      for (int i = 0; i < 4; ++i)
#pragma unroll
        for (int j = 0; j < 4; ++j) acc[i][j] = fmaf(a[i], b[j], acc[i][j]);
    }
    __syncthreads();
  }
#pragma unroll
  for (int i = 0; i < 4; ++i) {
    int r = m0 + ty * 4 + i;
#pragma unroll
    for (int j = 0; j < 4; ++j) {
      int c = n0 + tx * 4 + j;
      gi_all[(size_t)r * 1536 + c] =
          acc[i][j] + b_ih[c] + (c < 1024 ? b_hh[c] : 0.f);
    }
  }
}

// ---------------------------------------------------------------------------
// K3: split W_hh into bf16 hi/lo, pre-tiled into MFMA B-fragment layout.
// WBhi/WBlo layout: [cblk 0..31][s 0..2][ks 0..15][lane 0..63][8 bf16]
//   value = Whh_{hi,lo}[s*512 + cblk*16 + (lane&15)][ks*32 + (lane>>4)*8 + j]
// Also resets the grid-barrier counter for this launch (runs before k_rnn,
// stream-ordered, so safe under graph replay).
__global__ __launch_bounds__(256) void k_wsplit(
    const float* __restrict__ W_hh, __hip_bfloat16* __restrict__ WBhi,
    __hip_bfloat16* __restrict__ WBlo, unsigned int* bar) {
  if (blockIdx.x == 0 && threadIdx.x == 0) bar[0] = 0u;
  const int cblk = blockIdx.x & 31;
  const int s = blockIdx.x >> 5;  // 0..2
  const size_t tbase = (size_t)(cblk * 3 + s) * (16 * 64 * 8);
  for (int e = threadIdx.x; e < 8192; e += 256) {
    const int ks = e >> 9;
    const int rem = e & 511;
    const int l = rem >> 3;
    const int j = rem & 7;
    const int row = s * 512 + cblk * 16 + (l & 15);
    const int k = ks * 32 + ((l >> 4) * 8) + j;
    const float w = W_hh[(size_t)row * 512 + k];
    const __hip_bfloat16 hi = __float2bfloat16(w);
    const __hip_bfloat16 lo = __float2bfloat16(w - __bfloat162float(hi));
    const size_t idx = tbase + ((size_t)ks * 64 + l) * 8 + j;
    WBhi[idx] = hi;
    WBlo[idx] = lo;
  }
}

// ---------------------------------------------------------------------------
// Device-scope grid barrier (monotonic counter; bar reset per launch by
// k_wsplit). Co-residency is GUARANTEED by hipLaunchCooperativeKernel (the
// launcher falls back to the split-kernel path if coop launch is
// unavailable). Bounded spin (~0.2 s) turns any residual deadlock into a
// visible wrong-result failure instead of a hung container.
__device__ __forceinline__ void grid_barrier(unsigned int* bar,
                                             unsigned int target) {
  __threadfence();   // release: make hbuf/h_all stores agent-visible
  __syncthreads();
  if (threadIdx.x == 0) {
    __hip_atomic_fetch_add(bar, 1u, __ATOMIC_ACQ_REL, __HIP_MEMORY_SCOPE_AGENT);
    unsigned int spin = 0;
    while (__hip_atomic_load(bar, __ATOMIC_RELAXED, __HIP_MEMORY_SCOPE_AGENT) <
           target) {
      __builtin_amdgcn_s_sleep(2);
      if (++spin > (1u << 23)) break;  // safety valve: fail loud, not hung
    }
  }
  __syncthreads();
  __threadfence();   // acquire: invalidate stale cache lines before reads
}

// ---------------------------------------------------------------------------
// K4: the whole 31-step GRU recurrence in ONE cooperative launch.
// Grid 256 blocks x 256 thr. Block (mt = bid>>5, cblk = bid&31) owns the
// output patch b in [mt*16,mt*16+16), j in [cblk*16,cblk*16+16).
// gh = h @ W_hh^T computed as bf16x3 K=1536-concat MFMA GEMM:
//   seg0: Whi . hhi, seg1: Whi . hlo, seg2: Wlo . hhi   (drop Wlo.hlo ~2^-18)
// hbuf[b][0..511]=hhi, [512..1023]=hlo; seg2 A-cols read hhi again (c&1023).
// W fragments live in registers (3x12 short8 = 144 VGPR) across all steps.
// One grid barrier per step; ping-pong hbuf kills the write-after-read race.
__global__ __launch_bounds__(256, 1) void k_rnn(
    const float* __restrict__ h0, const float* __restrict__ gi_all,
    const __hip_bfloat16* __restrict__ WBhi,
    const __hip_bfloat16* __restrict__ WBlo, const float* __restrict__ b_hh,
    __hip_bfloat16* hbuf0, __hip_bfloat16* hbuf1,
    __hip_bfloat16* __restrict__ h_all, unsigned int* bar) {
  __shared__ float red[4][3][16][16];  // [wave][gate][col j][row b]
  const int tid = threadIdx.x;
  const int bid = blockIdx.x;
  const int cblk = bid & 31;  // h-column block (16 cols)
  const int mt = bid >> 5;    // batch tile (16 rows)
  const int wave = tid >> 6, lane = tid & 63;
  const int l16 = lane & 15, quad = lane >> 4;
  const int brow = tid >> 4, jcol = tid & 15;  // gates ownership
  const int bglob = mt * 16 + brow;
  const int jglob = cblk * 16 + jcol;

  // Preload step-invariant B fragments: wave covers concat k-steps
  // [wave*12, wave*12+12); kg<16 -> Whi[kg], kg<32 -> Whi[kg-16] (seg1:
  // same Whi, A side reads hlo), else Wlo[kg-32].
  short8 Bf[3][12];
#pragma unroll
  for (int s = 0; s < 3; ++s) {
#pragma unroll
    for (int ks = 0; ks < 12; ++ks) {
      const int kg = wave * 12 + ks;
      const unsigned short* src;
      int ks16;
      if (kg < 16) {
        src = (const unsigned short*)WBhi; ks16 = kg;
      } else if (kg < 32) {
        src = (const unsigned short*)WBhi; ks16 = kg - 16;
      } else {
        src = (const unsigned short*)WBlo; ks16 = kg - 32;
      }
      Bf[s][ks] = *(const short8*)(
          src + ((((size_t)(cblk * 3 + s) * 16 + ks16) * 64 + lane) * 8));
    }
  }

  const float bhn = b_hh[1024 + jglob];
  float h = h0[bglob * 512 + jglob];

  __hip_bfloat16* cur = hbuf0;
  __hip_bfloat16* nxt = hbuf1;
  {
    const __hip_bfloat16 hi = __float2bfloat16(h);
    cur[bglob * 1024 + jglob] = hi;
    cur[bglob * 1024 + 512 + jglob] =
        __float2bfloat16(h - __bfloat162float(hi));
  }
  unsigned int target = 256;
  grid_barrier(bar, target);

  for (int t = 0; t < 31; ++t) {
    // gi prefetch (independent of h) — issue before the MFMA phase
    const float* gi = gi_all + ((size_t)(t * 128 + bglob)) * 1536 + jglob;
    const float gir = gi[0];
    const float giz = gi[512];
    const float gin = gi[1024];

    // GH: wave computes its K-range of the 16x48 gh tile (3 gates)
    f32x4 acc0 = {0.f, 0.f, 0.f, 0.f};
    f32x4 acc1 = {0.f, 0.f, 0.f, 0.f};
    f32x4 acc2 = {0.f, 0.f, 0.f, 0.f};
    const unsigned short* arow =
        (const unsigned short*)cur + (size_t)(mt * 16 + l16) * 1024;
    const int cbase = wave * 384 + quad * 8;
#pragma unroll
    for (int ks = 0; ks < 12; ++ks) {
      const int c = (cbase + ks * 32) & 1023;  // seg2 re-reads hhi
      const short8 a = *(const short8*)(arow + c);
      acc0 = __builtin_amdgcn_mfma_f32_16x16x32_bf16(a, Bf[0][ks], acc0, 0, 0, 0);
      acc1 = __builtin_amdgcn_mfma_f32_16x16x32_bf16(a, Bf[1][ks], acc1, 0, 0, 0);
      acc2 = __builtin_amdgcn_mfma_f32_16x16x32_bf16(a, Bf[2][ks], acc2, 0, 0, 0);
    }
    // K-reduce across 4 waves via LDS. D frag: col=lane&15, row=quad*4+i.
    *(f32x4*)&red[wave][0][l16][quad * 4] = acc0;
    *(f32x4*)&red[wave][1][l16][quad * 4] = acc1;
    *(f32x4*)&red[wave][2][l16][quad * 4] = acc2;
    __syncthreads();
    float ghr = 0.f, ghz = 0.f, ghn = 0.f;
#pragma unroll
    for (int w = 0; w < 4; ++w) {
      ghr += red[w][0][jcol][brow];
      ghz += red[w][1][jcol][brow];
      ghn += red[w][2][jcol][brow];
    }
    ghn += bhn;
    const float r = 1.f / (1.f + __expf(-(gir + ghr)));
    const float z = 1.f / (1.f + __expf(-(giz + ghz)));
    const float n = tanhf(gin + r * ghn);
    h = (1.f - z) * n + z * h;

    const __hip_bfloat16 hi = __float2bfloat16(h);
    nxt[bglob * 1024 + jglob] = hi;
    nxt[bglob * 1024 + 512 + jglob] =
        __float2bfloat16(h - __bfloat162float(hi));
    h_all[((size_t)(t * 128 + bglob)) * 512 + jglob] = hi;

    if (t < 30) {
      target += 256;
      grid_barrier(bar, target);
      __hip_bfloat16* tmp = cur; cur = nxt; nxt = tmp;
    }
  }
}

// ---------------------------------------------------------------------------
// FALLBACK PATH (verbatim from the verified 1208 µs baseline):
// K3a: gh partials: gh[b][g] = h @ W_hh^T, split-K (4 chunks of 128).
__global__ __launch_bounds__(256) void k_gh(
    const float* __restrict__ h_cur, const float* __restrict__ W_hh,
    float* __restrict__ gh_part) {
  __shared__ float As[16][65];  // [k][m 0..63]
  __shared__ float Bs[16][36];  // [k][n 0..31]
  const int n0 = blockIdx.x * 32;
  const int m0 = blockIdx.y * 64;
  const int kz = blockIdx.z;  // K chunk of 128
  const int tid = threadIdx.x;
  const int tx = tid & 7, ty = tid >> 3;  // tx->n (4 each), ty->m (2 each)
  float acc[2][4] = {};
  for (int kt = 0; kt < 8; ++kt) {
    const int kbase = kz * 128 + kt * 16;
    const int kk = tid & 15, r0 = tid >> 4;
#pragma unroll
    for (int i = 0; i < 4; ++i) {
      int row = r0 + i * 16;
      As[kk][row] = h_cur[(size_t)(m0 + row) * 512 + kbase + kk];
    }
#pragma unroll
    for (int i = 0; i < 2; ++i) {
      int n = r0 + i * 16;
      Bs[kk][n] = W_hh[(size_t)(n0 + n) * 512 + kbase + kk];
    }
    __syncthreads();
#pragma unroll
    for (int k = 0; k < 16; ++k) {
      float a0 = As[k][ty * 2], a1 = As[k][ty * 2 + 1];
      float b[4];
#pragma unroll
      for (int j = 0; j < 4; ++j) b[j] = Bs[k][tx * 4 + j];
#pragma unroll
      for (int j = 0; j < 4; ++j) {
        acc[0][j] = fmaf(a0, b[j], acc[0][j]);
        acc[1][j] = fmaf(a1, b[j], acc[1][j]);
      }
    }
    __syncthreads();
  }
  float* dst = gh_part + (size_t)kz * (128 * 1536);
#pragma unroll
  for (int i = 0; i < 2; ++i) {
    int m = m0 + ty * 2 + i;
#pragma unroll
    for (int j = 0; j < 4; ++j)
      dst[(size_t)m * 1536 + n0 + tx * 4 + j] = acc[i][j];
  }
}

// K3b: gates + h update + bf16 cast of h into h_all[t]
__global__ __launch_bounds__(512) void k_gates(
    const float* __restrict__ gi_all, const float* __restrict__ gh_part,
    const float* __restrict__ b_hh, float* __restrict__ h_cur,
    __hip_bfloat16* __restrict__ h_all, int t) {
  const int b = blockIdx.x;    // 128
  const int j = threadIdx.x;   // 512
  const float* gi = gi_all + (size_t)(t * 128 + b) * 1536;
  float ghr = 0.f, ghz = 0.f, ghn = 0.f;
#pragma unroll
  for (int s = 0; s < 4; ++s) {
    const float* p = gh_part + (size_t)s * (128 * 1536) + (size_t)b * 1536;
    ghr += p[j];
    ghz += p[j + 512];
    ghn += p[j + 1024];
  }
  ghn += b_hh[1024 + j];
  float r = 1.f / (1.f + __expf(-(gi[j] + ghr)));
  float z = 1.f / (1.f + __expf(-(gi[j + 512] + ghz)));
  float n = tanhf(gi[j + 1024] + r * ghn);
  float h_old = h_cur[b * 512 + j];
  float hn = (1.f - z) * n + z * h_old;
  h_cur[b * 512 + j] = hn;
  h_all[((size_t)t * 128 + b) * 512 + j] = __float2bfloat16(hn);
}

// ---------------------------------------------------------------------------
// K5: transpose-convert W_cls [512,32000] f32 -> WT [32000,512] bf16
__global__ __launch_bounds__(256) void k_tcls(const float* __restrict__ W,
                                              __hip_bfloat16* __restrict__ WT) {
  __shared__ float tile[32][33];
  const int v0 = blockIdx.x * 32, k0 = blockIdx.y * 32;
  const int tx = threadIdx.x & 31, ty = threadIdx.x >> 5;  // 32x8
#pragma unroll
  for (int i = 0; i < 32; i += 8)
    tile[ty + i][tx] = W[(size_t)(k0 + ty + i) * 32000 + v0 + tx];  // [k][v]
  __syncthreads();
#pragma unroll
  for (int i = 0; i < 32; i += 8)
    WT[(size_t)(v0 + ty + i) * 512 + k0 + tx] = __float2bfloat16(tile[tx][ty + i]);
}

// ---------------------------------------------------------------------------
// K6: classifier GEMM, bf16 MFMA 16x16x32.
// C[r=t*128+b][v] = h_all[r,:] . WT[v,:] + b_cls[v]; out[(b*31+t)*32000+v]
// Tile 128x128, 4 waves (2x2 quadrants of 64x64), BK=64, K=512.
__global__ __launch_bounds__(256, 2) void k_cls_gemm(
    const __hip_bfloat16* __restrict__ Abf,   // [3968,512]
    const __hip_bfloat16* __restrict__ BTbf,  // [32000,512]
    const float* __restrict__ b_cls, float* __restrict__ out) {
  __shared__ unsigned short Al[128][72];  // [m][k], +8 pad
  __shared__ unsigned short Bl[128][72];  // [n][k], +8 pad
  const int nblk = blockIdx.x;  // 0..249
  const int tblk = blockIdx.y;  // 0..30 == t
  const int tid = threadIdx.x;
  const int wave = tid >> 6, lane = tid & 63;
  const int quad = lane >> 4, l16 = lane & 15;
  const int mw = (wave >> 1) * 64, nw = (wave & 1) * 64;

  f32x4 acc[4][4] = {};

  const unsigned short* Ag =
      (const unsigned short*)Abf + (size_t)tblk * 128 * 512;
  const unsigned short* Bg =
      (const unsigned short*)BTbf + (size_t)nblk * 128 * 512;

  for (int k0 = 0; k0 < 512; k0 += 64) {
    __syncthreads();  // protect previous iteration's reads
#pragma unroll
    for (int i = 0; i < 4; ++i) {
      int c = tid + i * 256;
      int row = c >> 3, c8 = c & 7;
      *(uint4*)(&Al[row][c8 * 8]) =
          *(const uint4*)(Ag + (size_t)row * 512 + k0 + c8 * 8);
      *(uint4*)(&Bl[row][c8 * 8]) =
          *(const uint4*)(Bg + (size_t)row * 512 + k0 + c8 * 8);
    }
    __syncthreads();
#pragma unroll
    for (int kc = 0; kc < 2; ++kc) {
      short8 a[4], b[4];
#pragma unroll
      for (int mt = 0; mt < 4; ++mt)
        a[mt] = *(const short8*)(&Al[mw + mt * 16 + l16][kc * 32 + quad * 8]);
#pragma unroll
      for (int nt = 0; nt < 4; ++nt)
        b[nt] = *(const short8*)(&Bl[nw + nt * 16 + l16][kc * 32 + quad * 8]);
#pragma unroll
      for (int mt = 0; mt < 4; ++mt)
#pragma unroll
        for (int nt = 0; nt < 4; ++nt)
          acc[mt][nt] = __builtin_amdgcn_mfma_f32_16x16x32_bf16(
              a[mt], b[nt], acc[mt][nt], 0, 0, 0);
    }
  }
  // epilogue: D row = quad*4+i, col = l16 within each 16x16 tile
#pragma unroll
  for (int nt = 0; nt < 4; ++nt) {
    int v = nblk * 128 + nw + nt * 16 + l16;
    float bc = b_cls[v];
#pragma unroll
    for (int mt = 0; mt < 4; ++mt) {
#pragma unroll
      for (int i = 0; i < 4; ++i) {
        int m = mw + mt * 16 + quad * 4 + i;  // == b (tile is one t)
        out[((size_t)m * 31 + tblk) * 32000 + v] = acc[mt][nt][i] + bc;
      }
    }
  }
}

// ---------------------------------------------------------------------------
extern "C" void kernel_launch(void* const* d_in, const int* in_sizes, int n_in,
                              void* d_out, int out_size, void* d_ws,
                              size_t ws_size, hipStream_t stream) {
  (void)in_sizes; (void)n_in; (void)out_size; (void)ws_size;
  const float* g_feat = (const float*)d_in[0];
  const float* t_feat = (const float*)d_in[1];
  const float* lang   = (const float*)d_in[2];
  // d_in[3] = lang_len (unused; num_words is static)
  const float* W_feat = (const float*)d_in[4];
  const float* b_feat = (const float*)d_in[5];
  const float* W_ih   = (const float*)d_in[6];
  const float* W_hh   = (const float*)d_in[7];
  const float* b_ih   = (const float*)d_in[8];
  const float* b_hh   = (const float*)d_in[9];
  const float* W_cls  = (const float*)d_in[10];
  const float* b_cls  = (const float*)d_in[11];
  float* out = (float*)d_out;

  char* ws = (char*)d_ws;
  float* h_cur          = (float*)(ws);                        // 256 KB
  unsigned int* bar     = (unsigned int*)(ws + 262144);        // 256 B
  __hip_bfloat16* WBhi  = (__hip_bfloat16*)(ws + 262400);      // 1.5 MB
  __hip_bfloat16* WBlo  = (__hip_bfloat16*)(ws + 1835264);     // 1.5 MB
  // fallback-only gh_part overlaps WBhi/WBlo (3 MB; unused on coop path)
  float* gh_part        = (float*)(ws + 262400);
  __hip_bfloat16* hbuf0 = (__hip_bfloat16*)(ws + 3408128);     // 256 KB
  __hip_bfloat16* hbuf1 = (__hip_bfloat16*)(ws + 3670272);     // 256 KB
  float* gi_all         = (float*)(ws + 3932416);              // 24.4 MB
  __hip_bfloat16* h_all = (__hip_bfloat16*)(ws + 28311808);    // 4 MB
  __hip_bfloat16* WT    = (__hip_bfloat16*)(ws + 32375040);    // 32.8 MB
  // total ws use: ~62.1 MB

  k_hidden0<<<128, 512, 0, stream>>>(g_feat, t_feat, W_feat, b_feat, h_cur);
  k_gi<<<dim3(24, 62), 256, 0, stream>>>(lang, W_ih, b_ih, b_hh, gi_all);
  k_tcls<<<dim3(1000, 16), 256, 0, stream>>>(W_cls, WT);

  // Recurrence: cooperative persistent kernel if available, else the
  // verified 62-dispatch baseline loop.
  static int coop_ok = -1;
  if (coop_ok < 0) {
    int v = 0;
    int dev = 0;
    hipGetDevice(&dev);
    if (hipDeviceGetAttribute(&v, hipDeviceAttributeCooperativeLaunch, dev) !=
        hipSuccess)
      v = 0;
    coop_ok = v;
  }
  bool did_coop = false;
  if (coop_ok == 1) {
    k_wsplit<<<96, 256, 0, stream>>>(W_hh, WBhi, WBlo, bar);
    const float* h0c = h_cur;
    void* kargs[] = {(void*)&h0c,   (void*)&gi_all, (void*)&WBhi,
                     (void*)&WBlo,  (void*)&b_hh,   (void*)&hbuf0,
                     (void*)&hbuf1, (void*)&h_all,  (void*)&bar};
    hipError_t e = hipLaunchCooperativeKernel(
        reinterpret_cast<void*>(k_rnn), dim3(256), dim3(256), kargs, 0,
        stream);
    did_coop = (e == hipSuccess);
  }
  if (!did_coop) {
    for (int t = 0; t < 31; ++t) {
      k_gh<<<dim3(48, 2, 4), 256, 0, stream>>>(h_cur, W_hh, gh_part);
      k_gates<<<128, 512, 0, stream>>>(gi_all, gh_part, b_hh, h_cur, h_all, t);
    }
  }
  k_cls_gemm<<<dim3(250, 31), 256, 0, stream>>>(h_all, WT, b_cls, out);
}

// Round 6
// 1036.967 us; speedup vs baseline: 2.3398x; 2.3398x over previous
//
#include <hip/hip_runtime.h>
#include <hip/hip_bf16.h>
#include <cstdint>
#include <cstddef>

typedef __attribute__((ext_vector_type(8))) short short8;
typedef __attribute__((ext_vector_type(4))) float f32x4;

// Shapes: B=128, T-1=31, E=300, H=512, 3H=1536, V=32000, M_ALL=3968

static __device__ __forceinline__ unsigned short bf_us(__hip_bfloat16 x) {
  union { __hip_bfloat16 b; unsigned short u; } v; v.b = x; return v.u;
}

// ---------------------------------------------------------------------------
// K1: hidden0 = relu(concat(g,t) @ W_feat + b_feat)   [128,256]@[256,512]
// Also writes h0 in split-plane bf16 hi/lo form into hb buffer 0 so k_rnn
// needs no initial exchange/barrier. (Cross-dispatch coherence is handled by
// kernel-end writeback; values identical across graph replays.)
__global__ __launch_bounds__(512) void k_hidden0(
    const float* __restrict__ g_feat, const float* __restrict__ t_feat,
    const float* __restrict__ W_feat, const float* __restrict__ b_feat,
    float* __restrict__ h_cur, unsigned short* __restrict__ hb0) {
  __shared__ float inp[256];
  const int b = blockIdx.x;
  const int tid = threadIdx.x;  // 512
  if (tid < 128) inp[tid] = g_feat[b * 128 + tid];
  else if (tid < 256) inp[tid] = t_feat[b * 128 + tid - 128];
  __syncthreads();
  float acc = b_feat[tid];
#pragma unroll 8
  for (int k = 0; k < 256; ++k) acc = fmaf(inp[k], W_feat[k * 512 + tid], acc);
  const float hn = fmaxf(acc, 0.f);
  h_cur[b * 512 + tid] = hn;
  const __hip_bfloat16 hi = __float2bfloat16(hn);
  const __hip_bfloat16 lo = __float2bfloat16(hn - __bfloat162float(hi));
  hb0[b * 1024 + tid] = bf_us(hi);
  hb0[b * 1024 + 512 + tid] = bf_us(lo);
}

// ---------------------------------------------------------------------------
// K2: gi_all[r=t*128+b][g] = x(t,b) @ W_ih^T + b_ih (+ b_hh for r,z gates)
// M=3968, N=1536, K=300. fp32 tiled SGEMM, BM=BN=64, BK=16, 4x4 micro.
__global__ __launch_bounds__(256) void k_gi(
    const float* __restrict__ lang, const float* __restrict__ W_ih,
    const float* __restrict__ b_ih, const float* __restrict__ b_hh,
    float* __restrict__ gi_all) {
  __shared__ float As[16][65];  // [k][m]
  __shared__ float Bs[16][65];  // [k][n]
  const int n0 = blockIdx.x * 64;
  const int m0 = blockIdx.y * 64;
  const int tid = threadIdx.x;
  const int tx = tid & 15, ty = tid >> 4;
  float acc[4][4] = {};
  for (int k0 = 0; k0 < 300; k0 += 16) {
    const int kk = tid & 15;
    const int r0 = tid >> 4;
    const int kg = k0 + kk;
    const bool kv = kg < 300;
#pragma unroll
    for (int i = 0; i < 4; ++i) {
      int row = r0 + i * 16;
      int r = m0 + row;
      int t = r >> 7, b = r & 127;
      As[kk][row] = kv ? lang[(size_t)b * 9600 + t * 300 + kg] : 0.f;
    }
#pragma unroll
    for (int i = 0; i < 4; ++i) {
      int n = r0 + i * 16;
      Bs[kk][n] = kv ? W_ih[(size_t)(n0 + n) * 300 + kg] : 0.f;
    }
    __syncthreads();
#pragma unroll
    for (int k = 0; k < 16; ++k) {
      float a[4], b[4];
#pragma unroll
      for (int i = 0; i < 4; ++i) a[i] = As[k][ty * 4 + i];
#pragma unroll
      for (int j = 0; j < 4; ++j) b[j] = Bs[k][tx * 4 + j];
#pragma unroll
      for (int i = 0; i < 4; ++i)
#pragma unroll
        for (int j = 0; j < 4; ++j) acc[i][j] = fmaf(a[i], b[j], acc[i][j]);
    }
    __syncthreads();
  }
#pragma unroll
  for (int i = 0; i < 4; ++i) {
    int r = m0 + ty * 4 + i;
#pragma unroll
    for (int j = 0; j < 4; ++j) {
      int c = n0 + tx * 4 + j;
      gi_all[(size_t)r * 1536 + c] =
          acc[i][j] + b_ih[c] + (c < 1024 ? b_hh[c] : 0.f);
    }
  }
}

// ---------------------------------------------------------------------------
// K3: split W_hh into bf16 hi/lo, pre-tiled into MFMA B-fragment layout.
// WBhi/WBlo layout: [cblk 0..31][s 0..2][ks 0..15][lane 0..63][8 bf16]
//   value = Whh_{hi,lo}[s*512 + cblk*16 + (lane&15)][ks*32 + (lane>>4)*8 + j]
// Also resets the per-group barrier counters via agent-scope atomic stores
// (coherent-point reset; stream-ordered before k_rnn; graph-replay safe).
__global__ __launch_bounds__(256) void k_wsplit(
    const float* __restrict__ W_hh, __hip_bfloat16* __restrict__ WBhi,
    __hip_bfloat16* __restrict__ WBlo, unsigned int* bar) {
  if (blockIdx.x == 0)
    __hip_atomic_store(&bar[threadIdx.x], 0u, __ATOMIC_RELAXED,
                       __HIP_MEMORY_SCOPE_AGENT);
  const int cblk = blockIdx.x & 31;
  const int s = blockIdx.x >> 5;  // 0..2
  const size_t tbase = (size_t)(cblk * 3 + s) * (16 * 64 * 8);
  for (int e = threadIdx.x; e < 8192; e += 256) {
    const int ks = e >> 9;
    const int rem = e & 511;
    const int l = rem >> 3;
    const int j = rem & 7;
    const int row = s * 512 + cblk * 16 + (l & 15);
    const int k = ks * 32 + ((l >> 4) * 8) + j;
    const float w = W_hh[(size_t)row * 512 + k];
    const __hip_bfloat16 hi = __float2bfloat16(w);
    const __hip_bfloat16 lo = __float2bfloat16(w - __bfloat162float(hi));
    const size_t idx = tbase + ((size_t)ks * 64 + l) * 8 + j;
    WBhi[idx] = hi;
    WBlo[idx] = lo;
  }
}

// ---------------------------------------------------------------------------
// Fence-free per-group barrier. Correctness recipe:
//  - cross-block h data is WRITTEN via agent-scope relaxed atomic stores
//    (write-through; vmcnt-ack => visible at the coherent point),
//  - __syncthreads() lowers to s_waitcnt vmcnt(0)+s_barrier, so every wave's
//    stores are acked before thread 0 arrives => add ordered after data,
//  - cross-block h data is READ via agent-scope relaxed atomic loads
//    (sc0 sc1: bypass L1/L2, served from the coherent point) => staleness is
//    impossible regardless of cache history (incl. across graph replays),
//  - trailing __syncthreads() is the compiler/order fence for the loads.
// NO __threadfence (no buffer_wbl2 / buffer_inv) anywhere in the loop.
// Bounded spin turns a residual deadlock into a visible wrong-result fail.
__device__ __forceinline__ void group_barrier(unsigned int* gbar,
                                              unsigned int target) {
  __syncthreads();
  if (threadIdx.x == 0) {
    __hip_atomic_fetch_add(gbar, 1u, __ATOMIC_RELAXED,
                           __HIP_MEMORY_SCOPE_AGENT);
    unsigned int spin = 0;
    while (__hip_atomic_load(gbar, __ATOMIC_RELAXED,
                             __HIP_MEMORY_SCOPE_AGENT) < target) {
      __builtin_amdgcn_s_sleep(8);
      if (++spin > (1u << 17)) break;  // ~0.1 s safety valve: fail loud
    }
  }
  __syncthreads();
}

// ---------------------------------------------------------------------------
// K4: the whole 31-step GRU recurrence in ONE cooperative launch.
// Grid 256 blocks x 256 thr. Block (mt = bid>>5, cblk = bid&31) owns the
// output patch b in [mt*16,+16), j in [cblk*16,+16).
// gh = h @ W_hh^T as bf16x3 K=1536-concat MFMA GEMM (drop Wlo.hlo ~2^-18).
// h exchanged through ping-pong buffers hb[2]: ushort[128][1024] per buffer
// (row: [0,512)=hhi plane, [512,1024)=hlo plane). Step t reads hb[t&1]
// (buffer 0 pre-filled by k_hidden0), writes hb[(t+1)&1].
// GRU rows are batch-independent, so sync is only among the 32 same-mt
// blocks: 8 independent per-mt barriers, ONE per step.
__global__ __launch_bounds__(256, 1) void k_rnn(
    const float* __restrict__ h0, const float* __restrict__ gi_all,
    const __hip_bfloat16* __restrict__ WBhi,
    const __hip_bfloat16* __restrict__ WBlo, const float* __restrict__ b_hh,
    unsigned short* hb,  // [2][128][1024] split-plane ping-pong buffers
    __hip_bfloat16* __restrict__ h_all, unsigned int* bar) {
  __shared__ float red[4][3][16][16];   // [wave][gate][col j][row b]
  __shared__ unsigned int exch[16][16]; // packed (lo<<16)|hi per (b,j)
  const int tid = threadIdx.x;
  const int bid = blockIdx.x;
  const int cblk = bid & 31;  // h-column block (16 cols)
  const int mt = bid >> 5;    // batch tile (16 rows)
  const int wave = tid >> 6, lane = tid & 63;
  const int l16 = lane & 15, quad = lane >> 4;
  const int brow = tid >> 4, jcol = tid & 15;  // gates ownership
  const int bglob = mt * 16 + brow;
  const int jglob = cblk * 16 + jcol;
  unsigned int* gbar = bar + mt * 32;  // per-group line, 128 B apart

  // Preload step-invariant B fragments: wave covers concat k-steps
  // [wave*12, wave*12+12); kg<16 -> Whi[kg] (A=hhi), kg<32 -> Whi[kg-16]
  // (A=hlo), else Wlo[kg-32] (A=hhi).
  short8 Bf[3][12];
#pragma unroll
  for (int s = 0; s < 3; ++s) {
#pragma unroll
    for (int ks = 0; ks < 12; ++ks) {
      const int kg = wave * 12 + ks;
      const unsigned short* src;
      int ks16;
      if (kg < 16) {
        src = (const unsigned short*)WBhi; ks16 = kg;
      } else if (kg < 32) {
        src = (const unsigned short*)WBhi; ks16 = kg - 16;
      } else {
        src = (const unsigned short*)WBlo; ks16 = kg - 32;
      }
      Bf[s][ks] = *(const short8*)(
          src + ((((size_t)(cblk * 3 + s) * 16 + ks16) * 64 + lane) * 8));
    }
  }

  const float bhn = b_hh[1024 + jglob];
  float h = h0[bglob * 512 + jglob];

  for (int t = 0; t < 31; ++t) {
    // gi prefetch (independent of h)
    const float* gi = gi_all + ((size_t)(t * 128 + bglob)) * 1536 + jglob;
    const float gir = gi[0];
    const float giz = gi[512];
    const float gin = gi[1024];

    // GH: wave computes its K-range of the 16x48 gh tile (3 gates).
    // A-fetch: agent-scope coherent loads (bypass L1/L2 -> never stale).
    f32x4 acc0 = {0.f, 0.f, 0.f, 0.f};
    f32x4 acc1 = {0.f, 0.f, 0.f, 0.f};
    f32x4 acc2 = {0.f, 0.f, 0.f, 0.f};
    const unsigned short* arow =
        hb + (size_t)(t & 1) * 131072 + (size_t)(mt * 16 + l16) * 1024;
    const int cbase = wave * 384 + quad * 8;
#pragma unroll
    for (int ks = 0; ks < 12; ++ks) {
      const int c = (cbase + ks * 32) & 1023;  // seg2 re-reads hhi plane
      const unsigned long long* ap = (const unsigned long long*)(arow + c);
      union { unsigned long long q[2]; short8 s; } u;
      u.q[0] = __hip_atomic_load(ap, __ATOMIC_RELAXED,
                                 __HIP_MEMORY_SCOPE_AGENT);
      u.q[1] = __hip_atomic_load(ap + 1, __ATOMIC_RELAXED,
                                 __HIP_MEMORY_SCOPE_AGENT);
      const short8 a = u.s;
      acc0 = __builtin_amdgcn_mfma_f32_16x16x32_bf16(a, Bf[0][ks], acc0, 0, 0, 0);
      acc1 = __builtin_amdgcn_mfma_f32_16x16x32_bf16(a, Bf[1][ks], acc1, 0, 0, 0);
      acc2 = __builtin_amdgcn_mfma_f32_16x16x32_bf16(a, Bf[2][ks], acc2, 0, 0, 0);
    }
    // K-reduce across 4 waves via LDS. D frag: col=lane&15, row=quad*4+i.
    *(f32x4*)&red[wave][0][l16][quad * 4] = acc0;
    *(f32x4*)&red[wave][1][l16][quad * 4] = acc1;
    *(f32x4*)&red[wave][2][l16][quad * 4] = acc2;
    __syncthreads();
    float ghr = 0.f, ghz = 0.f, ghn = 0.f;
#pragma unroll
    for (int w = 0; w < 4; ++w) {
      ghr += red[w][0][jcol][brow];
      ghz += red[w][1][jcol][brow];
      ghn += red[w][2][jcol][brow];
    }
    ghn += bhn;
    const float r = 1.f / (1.f + __expf(-(gir + ghr)));
    const float z = 1.f / (1.f + __expf(-(giz + ghz)));
    const float n = tanhf(gin + r * ghn);
    h = (1.f - z) * n + z * h;

    const __hip_bfloat16 hi = __float2bfloat16(h);
    h_all[((size_t)(t * 128 + bglob)) * 512 + jglob] = hi;  // normal store

    if (t < 30) {
      // Publish h for next step: LDS pair-exchange, then ONE u32
      // agent-scope atomic (write-through) store per thread.
      const __hip_bfloat16 lo = __float2bfloat16(h - __bfloat162float(hi));
      exch[brow][jcol] =
          (unsigned int)bf_us(hi) | ((unsigned int)bf_us(lo) << 16);
      __syncthreads();
      {
        const int pb = tid >> 4, q = tid & 15;
        const int plane = q & 1, pair = q >> 1;
        const unsigned int w0 = exch[pb][pair * 2];
        const unsigned int w1 = exch[pb][pair * 2 + 1];
        const unsigned int w = plane == 0
                                   ? ((w0 & 0xffffu) | (w1 << 16))
                                   : ((w0 >> 16) | (w1 & 0xffff0000u));
        unsigned int* dst = (unsigned int*)hb +
                            (size_t)((t + 1) & 1) * 65536 +
                            (size_t)(mt * 16 + pb) * 512 + plane * 256 +
                            cblk * 8 + pair;
        __hip_atomic_store(dst, w, __ATOMIC_RELAXED,
                           __HIP_MEMORY_SCOPE_AGENT);
      }
      group_barrier(gbar, (unsigned int)(t + 1) * 32);
    }
  }
}

// ---------------------------------------------------------------------------
// FALLBACK PATH (verbatim from the verified 1208 µs baseline):
// K3a: gh partials: gh[b][g] = h @ W_hh^T, split-K (4 chunks of 128).
__global__ __launch_bounds__(256) void k_gh(
    const float* __restrict__ h_cur, const float* __restrict__ W_hh,
    float* __restrict__ gh_part) {
  __shared__ float As[16][65];  // [k][m 0..63]
  __shared__ float Bs[16][36];  // [k][n 0..31]
  const int n0 = blockIdx.x * 32;
  const int m0 = blockIdx.y * 64;
  const int kz = blockIdx.z;  // K chunk of 128
  const int tid = threadIdx.x;
  const int tx = tid & 7, ty = tid >> 3;  // tx->n (4 each), ty->m (2 each)
  float acc[2][4] = {};
  for (int kt = 0; kt < 8; ++kt) {
    const int kbase = kz * 128 + kt * 16;
    const int kk = tid & 15, r0 = tid >> 4;
#pragma unroll
    for (int i = 0; i < 4; ++i) {
      int row = r0 + i * 16;
      As[kk][row] = h_cur[(size_t)(m0 + row) * 512 + kbase + kk];
    }
#pragma unroll
    for (int i = 0; i < 2; ++i) {
      int n = r0 + i * 16;
      Bs[kk][n] = W_hh[(size_t)(n0 + n) * 512 + kbase + kk];
    }
    __syncthreads();
#pragma unroll
    for (int k = 0; k < 16; ++k) {
      float a0 = As[k][ty * 2], a1 = As[k][ty * 2 + 1];
      float b[4];
#pragma unroll
      for (int j = 0; j < 4; ++j) b[j] = Bs[k][tx * 4 + j];
#pragma unroll
      for (int j = 0; j < 4; ++j) {
        acc[0][j] = fmaf(a0, b[j], acc[0][j]);
        acc[1][j] = fmaf(a1, b[j], acc[1][j]);
      }
    }
    __syncthreads();
  }
  float* dst = gh_part + (size_t)kz * (128 * 1536);
#pragma unroll
  for (int i = 0; i < 2; ++i) {
    int m = m0 + ty * 2 + i;
#pragma unroll
    for (int j = 0; j < 4; ++j)
      dst[(size_t)m * 1536 + n0 + tx * 4 + j] = acc[i][j];
  }
}

// K3b: gates + h update + bf16 cast of h into h_all[t]
__global__ __launch_bounds__(512) void k_gates(
    const float* __restrict__ gi_all, const float* __restrict__ gh_part,
    const float* __restrict__ b_hh, float* __restrict__ h_cur,
    __hip_bfloat16* __restrict__ h_all, int t) {
  const int b = blockIdx.x;    // 128
  const int j = threadIdx.x;   // 512
  const float* gi = gi_all + (size_t)(t * 128 + b) * 1536;
  float ghr = 0.f, ghz = 0.f, ghn = 0.f;
#pragma unroll
  for (int s = 0; s < 4; ++s) {
    const float* p = gh_part + (size_t)s * (128 * 1536) + (size_t)b * 1536;
    ghr += p[j];
    ghz += p[j + 512];
    ghn += p[j + 1024];
  }
  ghn += b_hh[1024 + j];
  float r = 1.f / (1.f + __expf(-(gi[j] + ghr)));
  float z = 1.f / (1.f + __expf(-(gi[j + 512] + ghz)));
  float n = tanhf(gi[j + 1024] + r * ghn);
  float h_old = h_cur[b * 512 + j];
  float hn = (1.f - z) * n + z * h_old;
  h_cur[b * 512 + j] = hn;
  h_all[((size_t)t * 128 + b) * 512 + j] = __float2bfloat16(hn);
}

// ---------------------------------------------------------------------------
// K5: transpose-convert W_cls [512,32000] f32 -> WT [32000,512] bf16
__global__ __launch_bounds__(256) void k_tcls(const float* __restrict__ W,
                                              __hip_bfloat16* __restrict__ WT) {
  __shared__ float tile[32][33];
  const int v0 = blockIdx.x * 32, k0 = blockIdx.y * 32;
  const int tx = threadIdx.x & 31, ty = threadIdx.x >> 5;  // 32x8
#pragma unroll
  for (int i = 0; i < 32; i += 8)
    tile[ty + i][tx] = W[(size_t)(k0 + ty + i) * 32000 + v0 + tx];  // [k][v]
  __syncthreads();
#pragma unroll
  for (int i = 0; i < 32; i += 8)
    WT[(size_t)(v0 + ty + i) * 512 + k0 + tx] = __float2bfloat16(tile[tx][ty + i]);
}

// ---------------------------------------------------------------------------
// K6: classifier GEMM, bf16 MFMA 16x16x32.
// C[r=t*128+b][v] = h_all[r,:] . WT[v,:] + b_cls[v]; out[(b*31+t)*32000+v]
// Tile 128x128, 4 waves (2x2 quadrants of 64x64), BK=64, K=512.
__global__ __launch_bounds__(256, 2) void k_cls_gemm(
    const __hip_bfloat16* __restrict__ Abf,   // [3968,512]
    const __hip_bfloat16* __restrict__ BTbf,  // [32000,512]
    const float* __restrict__ b_cls, float* __restrict__ out) {
  __shared__ unsigned short Al[128][72];  // [m][k], +8 pad
  __shared__ unsigned short Bl[128][72];  // [n][k], +8 pad
  const int nblk = blockIdx.x;  // 0..249
  const int tblk = blockIdx.y;  // 0..30 == t
  const int tid = threadIdx.x;
  const int wave = tid >> 6, lane = tid & 63;
  const int quad = lane >> 4, l16 = lane & 15;
  const int mw = (wave >> 1) * 64, nw = (wave & 1) * 64;

  f32x4 acc[4][4] = {};

  const unsigned short* Ag =
      (const unsigned short*)Abf + (size_t)tblk * 128 * 512;
  const unsigned short* Bg =
      (const unsigned short*)BTbf + (size_t)nblk * 128 * 512;

  for (int k0 = 0; k0 < 512; k0 += 64) {
    __syncthreads();  // protect previous iteration's reads
#pragma unroll
    for (int i = 0; i < 4; ++i) {
      int c = tid + i * 256;
      int row = c >> 3, c8 = c & 7;
      *(uint4*)(&Al[row][c8 * 8]) =
          *(const uint4*)(Ag + (size_t)row * 512 + k0 + c8 * 8);
      *(uint4*)(&Bl[row][c8 * 8]) =
          *(const uint4*)(Bg + (size_t)row * 512 + k0 + c8 * 8);
    }
    __syncthreads();
#pragma unroll
    for (int kc = 0; kc < 2; ++kc) {
      short8 a[4], b[4];
#pragma unroll
      for (int mt = 0; mt < 4; ++mt)
        a[mt] = *(const short8*)(&Al[mw + mt * 16 + l16][kc * 32 + quad * 8]);
#pragma unroll
      for (int nt = 0; nt < 4; ++nt)
        b[nt] = *(const short8*)(&Bl[nw + nt * 16 + l16][kc * 32 + quad * 8]);
#pragma unroll
      for (int mt = 0; mt < 4; ++mt)
#pragma unroll
        for (int nt = 0; nt < 4; ++nt)
          acc[mt][nt] = __builtin_amdgcn_mfma_f32_16x16x32_bf16(
              a[mt], b[nt], acc[mt][nt], 0, 0, 0);
    }
  }
  // epilogue: D row = quad*4+i, col = l16 within each 16x16 tile
#pragma unroll
  for (int nt = 0; nt < 4; ++nt) {
    int v = nblk * 128 + nw + nt * 16 + l16;
    float bc = b_cls[v];
#pragma unroll
    for (int mt = 0; mt < 4; ++mt) {
#pragma unroll
      for (int i = 0; i < 4; ++i) {
        int m = mw + mt * 16 + quad * 4 + i;  // == b (tile is one t)
        out[((size_t)m * 31 + tblk) * 32000 + v] = acc[mt][nt][i] + bc;
      }
    }
  }
}

// ---------------------------------------------------------------------------
extern "C" void kernel_launch(void* const* d_in, const int* in_sizes, int n_in,
                              void* d_out, int out_size, void* d_ws,
                              size_t ws_size, hipStream_t stream) {
  (void)in_sizes; (void)n_in; (void)out_size;
  const float* g_feat = (const float*)d_in[0];
  const float* t_feat = (const float*)d_in[1];
  const float* lang   = (const float*)d_in[2];
  // d_in[3] = lang_len (unused; num_words is static)
  const float* W_feat = (const float*)d_in[4];
  const float* b_feat = (const float*)d_in[5];
  const float* W_ih   = (const float*)d_in[6];
  const float* W_hh   = (const float*)d_in[7];
  const float* b_ih   = (const float*)d_in[8];
  const float* b_hh   = (const float*)d_in[9];
  const float* W_cls  = (const float*)d_in[10];
  const float* b_cls  = (const float*)d_in[11];
  float* out = (float*)d_out;

  char* ws = (char*)d_ws;
  // Layout (~65.1 MB total; round 2 proved ws_size >= 73 MB):
  float* h_cur          = (float*)(ws);                        // 256 KB
  unsigned int* bar     = (unsigned int*)(ws + 262144);        // 1 KB (pad 4K)
  __hip_bfloat16* WBhi  = (__hip_bfloat16*)(ws + 266240);      // 1.5 MB
  __hip_bfloat16* WBlo  = (__hip_bfloat16*)(ws + 1839104);     // 1.5 MB
  float* gh_part        = (float*)(ws + 266240);               // alias, fb-only
  unsigned short* hb    = (unsigned short*)(ws + 3411968);     // 512 KB
  float* gi_all         = (float*)(ws + 3936256);              // 24.4 MB
  __hip_bfloat16* h_all = (__hip_bfloat16*)(ws + 28315648);    // 4 MB
  __hip_bfloat16* WT    = (__hip_bfloat16*)(ws + 32378880);    // 32.8 MB
  const size_t WS_NEED_COOP = 65146880;

  k_hidden0<<<128, 512, 0, stream>>>(g_feat, t_feat, W_feat, b_feat, h_cur,
                                     hb);
  k_gi<<<dim3(24, 62), 256, 0, stream>>>(lang, W_ih, b_ih, b_hh, gi_all);
  k_tcls<<<dim3(1000, 16), 256, 0, stream>>>(W_cls, WT);

  // Recurrence: cooperative persistent kernel if available + ws fits,
  // else the verified 62-dispatch baseline loop.
  static int coop_ok = -1;
  if (coop_ok < 0) {
    int v = 0;
    int dev = 0;
    hipGetDevice(&dev);
    if (hipDeviceGetAttribute(&v, hipDeviceAttributeCooperativeLaunch, dev) !=
        hipSuccess)
      v = 0;
    coop_ok = v;
  }
  bool did_coop = false;
  if (coop_ok == 1 && ws_size >= WS_NEED_COOP) {
    k_wsplit<<<96, 256, 0, stream>>>(W_hh, WBhi, WBlo, bar);
    const float* h0c = h_cur;
    void* kargs[] = {(void*)&h0c,  (void*)&gi_all, (void*)&WBhi,
                     (void*)&WBlo, (void*)&b_hh,   (void*)&hb,
                     (void*)&h_all, (void*)&bar};
    hipError_t e = hipLaunchCooperativeKernel(
        reinterpret_cast<void*>(k_rnn), dim3(256), dim3(256), kargs, 0,
        stream);
    did_coop = (e == hipSuccess);
  }
  if (!did_coop) {
    for (int t = 0; t < 31; ++t) {
      k_gh<<<dim3(48, 2, 4), 256, 0, stream>>>(h_cur, W_hh, gh_part);
      k_gates<<<128, 512, 0, stream>>>(gi_all, gh_part, b_hh, h_cur, h_all, t);
    }
  }
  k_cls_gemm<<<dim3(250, 31), 256, 0, stream>>>(h_all, WT, b_cls, out);
}